// Round 3
// baseline (194.309 us; speedup 1.0000x reference)
//
#include <hip/hip_runtime.h>
#include <stdint.h>

typedef unsigned short u16;
typedef short bf8 __attribute__((ext_vector_type(8)));   // 8 bf16 (bit pattern)
typedef float f4 __attribute__((ext_vector_type(4)));

#define TTOK 8192
#define HD   1024
#define NE   8

static __device__ __forceinline__ u16 f2bf(float f) {
  union { float f; uint32_t u; } v; v.f = f;
  return (u16)((v.u + 0x7fffu + ((v.u >> 16) & 1u)) >> 16);   // RNE
}

// ---------------- gating (fp32) + x -> bf16 conversion ----------------
__global__ __launch_bounds__(256) void gate_conv_kernel(
    const float* __restrict__ x, const float* __restrict__ gw,
    const float* __restrict__ gb, float* __restrict__ wout,
    u16* __restrict__ abf)
{
  const int t    = blockIdx.x * 4 + (threadIdx.x >> 6);
  const int lane = threadIdx.x & 63;
  const float* xr = x + (size_t)t * HD;
  float p[NE];
#pragma unroll
  for (int e = 0; e < NE; ++e) p[e] = 0.f;
#pragma unroll 4
  for (int h = lane; h < HD; h += 64) {
    const float xv = xr[h];
    abf[(size_t)t * HD + h] = f2bf(xv);
    const float* g = gw + (size_t)h * NE;
#pragma unroll
    for (int e = 0; e < NE; ++e) p[e] += xv * g[e];
  }
#pragma unroll
  for (int e = 0; e < NE; ++e) {
#pragma unroll
    for (int off = 32; off > 0; off >>= 1)
      p[e] += __shfl_xor(p[e], off, 64);
    p[e] += gb[e];
  }
  float m = p[0];
#pragma unroll
  for (int e = 1; e < NE; ++e) m = fmaxf(m, p[e]);
  float s = 0.f;
#pragma unroll
  for (int e = 0; e < NE; ++e) { p[e] = expf(p[e] - m); s += p[e]; }
  const float inv = 1.f / s;
  if (lane == 0) {
#pragma unroll
    for (int e = 0; e < NE; ++e) wout[t * NE + e] = p[e] * inv;
  }
}

// ------------- expert_w [E][H][H] fp32 -> Wt [E][d][h] bf16 (transposed) -------------
__global__ __launch_bounds__(256) void wconv_kernel(
    const float* __restrict__ ew, u16* __restrict__ wt)
{
  __shared__ u16 tile[64][66];
  const int e  = blockIdx.z;
  const int h0 = blockIdx.y * 64;
  const int d0 = blockIdx.x * 64;
  const int c  = threadIdx.x & 63;
  const int r0 = threadIdx.x >> 6;
  const float* src = ew + (size_t)e * HD * HD;
  u16* dst = wt + (size_t)e * HD * HD;
#pragma unroll
  for (int i = 0; i < 16; ++i) {
    const int r = i * 4 + r0;
    tile[r][c] = f2bf(src[(size_t)(h0 + r) * HD + d0 + c]);
  }
  __syncthreads();
#pragma unroll
  for (int i = 0; i < 16; ++i) {
    const int r = i * 4 + r0;
    dst[(size_t)(d0 + r) * HD + h0 + c] = tile[c][r];
  }
}

// ---------------- fused dense-MoE GEMM, 8-phase-style schedule ----------------
// out[t,d] = sum_e w[t,e] * ( sum_k A[t,k] * Wt[e][d][k] + eb[e][d] )
#define BM 256
#define BN 128
#define BK 64

#define MM(a_, b_, c_) __builtin_amdgcn_mfma_f32_16x16x32_bf16((a_), (b_), (c_), 0, 0, 0)

// LDS read: row r, granule g (16B) stored at slot g^(r&7)  (involution, matches staging)
#define LDA(C, m, kk) (*(const bf8*)((const char*)As + (C) * 32768 + \
    (wrb + (m) * 16 + l15) * 128 + ((((kk) * 4 + lhi) ^ (l15 & 7)) << 4)))
#define LDB(C, n, kk) (*(const bf8*)((const char*)Bs + (C) * 16384 + \
    (wcb + (n) * 16 + l15) * 128 + ((((kk) * 4 + lhi) ^ (l15 & 7)) << 4)))

#define GLA(j) __builtin_amdgcn_global_load_lds( \
    (const __attribute__((address_space(1))) void*)(aSrcT + (size_t)(j) * 65536), \
    (__attribute__((address_space(3))) void*)(aDstT + (j) * 8192), 16, 0, 0)
#define GLB(j) __builtin_amdgcn_global_load_lds( \
    (const __attribute__((address_space(1))) void*)(bSrcT + (size_t)(j) * 65536), \
    (__attribute__((address_space(3))) void*)(bDstT + (j) * 8192), 16, 0, 0)

#define MFMA4(n_, b_) \
    acc[0][n_] = MM(a0, (b_), acc[0][n_]); \
    acc[1][n_] = MM(a1, (b_), acc[1][n_]); \
    acc[2][n_] = MM(a2, (b_), acc[2][n_]); \
    acc[3][n_] = MM(a3, (b_), acc[3][n_]);

#define PRE_MFMA  __builtin_amdgcn_s_barrier(); \
                  __builtin_amdgcn_sched_barrier(0); \
                  __builtin_amdgcn_s_setprio(1);
#define POST_MFMA __builtin_amdgcn_s_setprio(0); \
                  __builtin_amdgcn_sched_barrier(0); \
                  __builtin_amdgcn_s_barrier();

#define TILE(qexpr, C)                                                          \
  {                                                                             \
    const int q_  = (qexpr);                                                    \
    const int qn_ = (q_ < 127) ? (q_ + 1) : 127;                                \
    const int en_ = qn_ >> 4;                                                   \
    const int kcn_ = (qn_ & 15) << 6;                                           \
    const u16* aSrcT = aSrc0 + kcn_;                                            \
    const u16* bSrcT = bSrc0 + (size_t)en_ * (HD * HD) + kcn_;                  \
    char* aDstT = aDstB + ((C) ^ 1) * 32768;                                    \
    char* bDstT = bDstB + ((C) ^ 1) * 16384;                                    \
    bf8 a0, a1, a2, a3, b0, b1;                                                 \
    /* P0: kk0, n0/n1 */                                                        \
    a0 = LDA(C, 0, 0); a1 = LDA(C, 1, 0); a2 = LDA(C, 2, 0); a3 = LDA(C, 3, 0);  \
    b0 = LDB(C, 0, 0); b1 = LDB(C, 1, 0);                                       \
    GLA(0); GLA(1); GLB(0);                                                     \
    PRE_MFMA                                                                    \
    MFMA4(0, b0) MFMA4(1, b1)                                                   \
    POST_MFMA                                                                   \
    /* P1: kk0, n2/n3 */                                                        \
    b0 = LDB(C, 2, 0); b1 = LDB(C, 3, 0);                                       \
    GLA(2); GLA(3); GLB(1);                                                     \
    PRE_MFMA                                                                    \
    MFMA4(2, b0) MFMA4(3, b1)                                                   \
    POST_MFMA                                                                   \
    /* P2: kk1, n0/n1 */                                                        \
    a0 = LDA(C, 0, 1); a1 = LDA(C, 1, 1); a2 = LDA(C, 2, 1); a3 = LDA(C, 3, 1);  \
    b0 = LDB(C, 0, 1); b1 = LDB(C, 1, 1);                                       \
    PRE_MFMA                                                                    \
    MFMA4(0, b0) MFMA4(1, b1)                                                   \
    POST_MFMA                                                                   \
    /* P3: kk1, n2/n3 */                                                        \
    b0 = LDB(C, 2, 1); b1 = LDB(C, 3, 1);                                       \
    __builtin_amdgcn_s_barrier();                                               \
    __builtin_amdgcn_sched_barrier(0);                                          \
    __builtin_amdgcn_s_setprio(1);                                              \
    MFMA4(2, b0) MFMA4(3, b1)                                                   \
    __builtin_amdgcn_s_setprio(0);                                              \
    __builtin_amdgcn_sched_barrier(0);                                          \
    asm volatile("s_waitcnt vmcnt(0)" ::: "memory");                            \
    __builtin_amdgcn_s_barrier();                                               \
  }

__global__ __launch_bounds__(512, 2) void moe_gemm_kernel(
    const u16* __restrict__ A,      // [T][H] bf16
    const u16* __restrict__ Wt,     // [E][H(d)][H(k)] bf16
    const float* __restrict__ wg,   // [T][E]
    const float* __restrict__ eb,   // [E][H]
    float* __restrict__ out)        // [T][H] fp32
{
  __shared__ u16 As[2 * BM * BK];   // 64 KB (2 buffers)
  __shared__ u16 Bs[2 * BN * BK];   // 32 KB

  const int bid   = blockIdx.x;
  const int xcd   = bid & 7;
  const int local = bid >> 3;
  const int bm    = xcd * 4 + (local & 3);   // 32 bm total, 4 per XCD
  const int bn    = local >> 2;              // 8 bn
  const int row0  = bm * BM;
  const int col0  = bn * BN;

  const int tid  = threadIdx.x;
  const int lane = tid & 63;
  const int wid  = tid >> 6;
  const int wr   = wid >> 1;        // 0..3
  const int wc   = wid & 1;         // 0..1
  const int l15  = lane & 15;
  const int lhi  = lane >> 4;
  const int wrb  = wr * 64;
  const int wcb  = wc * 64;

  // staging constants: 512 thr x 16B = 8KB/round; round j covers rows j*64..j*64+63
  const int row_in = tid >> 3;                       // 0..63
  const int gsw    = (tid & 7) ^ ((tid >> 3) & 7);   // pre-swizzled source granule
  const u16* aSrc0 = A  + (size_t)(row0 + row_in) * HD + gsw * 8;
  const u16* bSrc0 = Wt + (size_t)(col0 + row_in) * HD + gsw * 8;
  char* aDstB = (char*)As + tid * 16;
  char* bDstB = (char*)Bs + tid * 16;

  const f4 fz = {0.f, 0.f, 0.f, 0.f};
  f4 acc[4][4], accO[4][4];
#pragma unroll
  for (int i = 0; i < 4; ++i)
#pragma unroll
    for (int j = 0; j < 4; ++j) { acc[i][j] = fz; accO[i][j] = fz; }

  // prologue: stage tile 0 (e=0, kcol=0) into buffer 0
  {
    const u16* aSrcT = aSrc0;
    const u16* bSrcT = bSrc0;
    char* aDstT = aDstB;
    char* bDstT = bDstB;
    GLA(0); GLA(1); GLA(2); GLA(3); GLB(0); GLB(1);
  }
  asm volatile("s_waitcnt vmcnt(0)" ::: "memory");
  __builtin_amdgcn_s_barrier();

  for (int e = 0; e < NE; ++e) {
    for (int kt2 = 0; kt2 < 8; ++kt2) {
      const int qb = e * 16 + kt2 * 2;
      TILE(qb, 0)
      TILE(qb + 1, 1)
    }
    // fold expert e into output accumulator with per-row gate weight
#pragma unroll
    for (int mi = 0; mi < 4; ++mi) {
      const int tb = row0 + wrb + mi * 16 + lhi * 4;
      const float w0 = wg[(size_t)(tb + 0) * NE + e];
      const float w1 = wg[(size_t)(tb + 1) * NE + e];
      const float w2 = wg[(size_t)(tb + 2) * NE + e];
      const float w3 = wg[(size_t)(tb + 3) * NE + e];
#pragma unroll
      for (int ni = 0; ni < 4; ++ni) {
        accO[mi][ni][0] += w0 * acc[mi][ni][0];
        accO[mi][ni][1] += w1 * acc[mi][ni][1];
        accO[mi][ni][2] += w2 * acc[mi][ni][2];
        accO[mi][ni][3] += w3 * acc[mi][ni][3];
        acc[mi][ni] = fz;
      }
    }
  }

  // epilogue: gated bias + store (C/D: col = lane&15, row = (lane>>4)*4 + reg)
  float ebv[4][8];
#pragma unroll
  for (int ni = 0; ni < 4; ++ni) {
    const int d = col0 + wcb + ni * 16 + l15;
#pragma unroll
    for (int e2 = 0; e2 < NE; ++e2) ebv[ni][e2] = eb[(size_t)e2 * HD + d];
  }
#pragma unroll
  for (int mi = 0; mi < 4; ++mi) {
    const int tb = row0 + wrb + mi * 16 + lhi * 4;
#pragma unroll
    for (int j = 0; j < 4; ++j) {
      const int t = tb + j;
      const f4 wlo = *(const f4*)(wg + (size_t)t * NE);
      const f4 whi = *(const f4*)(wg + (size_t)t * NE + 4);
#pragma unroll
      for (int ni = 0; ni < 4; ++ni) {
        const float bias =
            wlo[0] * ebv[ni][0] + wlo[1] * ebv[ni][1] +
            wlo[2] * ebv[ni][2] + wlo[3] * ebv[ni][3] +
            whi[0] * ebv[ni][4] + whi[1] * ebv[ni][5] +
            whi[2] * ebv[ni][6] + whi[3] * ebv[ni][7];
        const int d = col0 + wcb + ni * 16 + l15;
        out[(size_t)t * HD + d] = accO[mi][ni][j] + bias;
      }
    }
  }
}

extern "C" void kernel_launch(void* const* d_in, const int* in_sizes, int n_in,
                              void* d_out, int out_size, void* d_ws, size_t ws_size,
                              hipStream_t stream) {
  const float* x  = (const float*)d_in[0];   // [4,2048,1024]
  const float* gw = (const float*)d_in[1];   // [1024,8]
  const float* gb = (const float*)d_in[2];   // [8]
  const float* ew = (const float*)d_in[3];   // [8,1024,1024]
  const float* eb = (const float*)d_in[4];   // [8,1024]
  float* out = (float*)d_out;                // [4,2048,1024] fp32

  char* ws = (char*)d_ws;
  u16*   abf   = (u16*)ws;                                // 16 MB bf16 x
  u16*   wt    = (u16*)(ws + (size_t)16 * 1024 * 1024);   // 16 MB bf16 Wt
  float* wgate = (float*)(ws + (size_t)32 * 1024 * 1024); // 256 KB gate weights

  gate_conv_kernel<<<dim3(TTOK / 4), dim3(256), 0, stream>>>(x, gw, gb, wgate, abf);
  wconv_kernel<<<dim3(16, 16, 8), dim3(256), 0, stream>>>(ew, wt);
  moe_gemm_kernel<<<dim3((TTOK / BM) * (HD / BN)), dim3(512), 0, stream>>>(abf, wt, wgate, eb, out);
}

// Round 4
// 191.247 us; speedup vs baseline: 1.0160x; 1.0160x over previous
//
#include <hip/hip_runtime.h>
#include <stdint.h>

typedef unsigned short u16;
typedef short bf8 __attribute__((ext_vector_type(8)));   // 8 bf16 (bit pattern)
typedef float f4 __attribute__((ext_vector_type(4)));

#define TTOK 8192
#define HD   1024
#define NE   8

static __device__ __forceinline__ u16 f2bf(float f) {
  union { float f; uint32_t u; } v; v.f = f;
  return (u16)((v.u + 0x7fffu + ((v.u >> 16) & 1u)) >> 16);   // RNE
}

// ---------------- gating (fp32) + x -> bf16 conversion ----------------
__global__ __launch_bounds__(256) void gate_conv_kernel(
    const float* __restrict__ x, const float* __restrict__ gw,
    const float* __restrict__ gb, float* __restrict__ wout,
    u16* __restrict__ abf)
{
  const int t    = blockIdx.x * 4 + (threadIdx.x >> 6);
  const int lane = threadIdx.x & 63;
  const float* xr = x + (size_t)t * HD;
  float p[NE];
#pragma unroll
  for (int e = 0; e < NE; ++e) p[e] = 0.f;
#pragma unroll 4
  for (int h = lane; h < HD; h += 64) {
    const float xv = xr[h];
    abf[(size_t)t * HD + h] = f2bf(xv);
    const float* g = gw + (size_t)h * NE;
#pragma unroll
    for (int e = 0; e < NE; ++e) p[e] += xv * g[e];
  }
#pragma unroll
  for (int e = 0; e < NE; ++e) {
#pragma unroll
    for (int off = 32; off > 0; off >>= 1)
      p[e] += __shfl_xor(p[e], off, 64);
    p[e] += gb[e];
  }
  float m = p[0];
#pragma unroll
  for (int e = 1; e < NE; ++e) m = fmaxf(m, p[e]);
  float s = 0.f;
#pragma unroll
  for (int e = 0; e < NE; ++e) { p[e] = expf(p[e] - m); s += p[e]; }
  const float inv = 1.f / s;
  if (lane == 0) {
#pragma unroll
    for (int e = 0; e < NE; ++e) wout[t * NE + e] = p[e] * inv;
  }
}

// ------------- expert_w [E][H][H] fp32 -> Wt [E][d][h] bf16 (transposed) -------------
__global__ __launch_bounds__(256) void wconv_kernel(
    const float* __restrict__ ew, u16* __restrict__ wt)
{
  __shared__ u16 tile[64][66];
  const int e  = blockIdx.z;
  const int h0 = blockIdx.y * 64;
  const int d0 = blockIdx.x * 64;
  const int c  = threadIdx.x & 63;
  const int r0 = threadIdx.x >> 6;
  const float* src = ew + (size_t)e * HD * HD;
  u16* dst = wt + (size_t)e * HD * HD;
#pragma unroll
  for (int i = 0; i < 16; ++i) {
    const int r = i * 4 + r0;
    tile[r][c] = f2bf(src[(size_t)(h0 + r) * HD + d0 + c]);
  }
  __syncthreads();
#pragma unroll
  for (int i = 0; i < 16; ++i) {
    const int r = i * 4 + r0;
    dst[(size_t)(d0 + r) * HD + h0 + c] = tile[c][r];
  }
}

// ---------------- fused dense-MoE GEMM — ring-3 counted-vmcnt pipeline ----------------
// out[t,d] = sum_e w[t,e] * ( sum_k A[t,k] * Wt[e][d][k] + eb[e][d] )
#define BM 256
#define BN 128
#define BK 64

#define MM(a_, b_, c_) __builtin_amdgcn_mfma_f32_16x16x32_bf16((a_), (b_), (c_), 0, 0, 0)

// row-major [rows][BK] tile, 128 B/row; granule g (16B) stored at slot g^(row&7)
#define LDF(base_, row_, kk_) \
  (*(const bf8*)((base_) + (size_t)(row_) * 128 + ((((kk_) * 4 + lhi) ^ ((row_) & 7)) << 4)))

#define GL(srcp_, dstp_) __builtin_amdgcn_global_load_lds( \
    (const __attribute__((address_space(1))) void*)(srcp_), \
    (__attribute__((address_space(3))) void*)(dstp_), 16, 0, 0)

// stage tile sq: A 4 rounds (64 rows each), B 2 rounds; dest linear, source pre-swizzled
#define STAGE(sq_, stA_, stB_)                                      \
  {                                                                 \
    const int se_ = (sq_) >> 4;                                     \
    const int sk_ = ((sq_) & 15) << 6;                              \
    const u16* as_ = aSrc0 + sk_;                                   \
    const u16* bs_ = bSrc0 + (size_t)se_ * (HD * HD) + sk_;         \
    char* ad_ = (char*)As + (stA_) + tid * 16;                      \
    char* bd_ = (char*)Bs + (stB_) + tid * 16;                      \
    GL(as_,          ad_);                                          \
    GL(as_ +  65536, ad_ +  8192);                                  \
    GL(as_ + 131072, ad_ + 16384);                                  \
    GL(as_ + 196608, ad_ + 24576);                                  \
    GL(bs_,          bd_);                                          \
    GL(bs_ +  65536, bd_ +  8192);                                  \
  }

#define MFMA4(n_, b_) \
    acc[0][n_] = MM(a0, (b_), acc[0][n_]); \
    acc[1][n_] = MM(a1, (b_), acc[1][n_]); \
    acc[2][n_] = MM(a2, (b_), acc[2][n_]); \
    acc[3][n_] = MM(a3, (b_), acc[3][n_]);

#define COMPUTE_HALF(ab_, bb_, kk_)                      \
  {                                                      \
    bf8 a0 = LDF(ab_, wrb +  0 + l15, kk_);              \
    bf8 a1 = LDF(ab_, wrb + 16 + l15, kk_);              \
    bf8 a2 = LDF(ab_, wrb + 32 + l15, kk_);              \
    bf8 a3 = LDF(ab_, wrb + 48 + l15, kk_);              \
    bf8 b0 = LDF(bb_, wcb +  0 + l15, kk_);              \
    bf8 b1 = LDF(bb_, wcb + 16 + l15, kk_);              \
    bf8 b2 = LDF(bb_, wcb + 32 + l15, kk_);              \
    bf8 b3 = LDF(bb_, wcb + 48 + l15, kk_);              \
    __builtin_amdgcn_s_setprio(1);                       \
    MFMA4(0, b0) MFMA4(1, b1) MFMA4(2, b2) MFMA4(3, b3)  \
    __builtin_amdgcn_s_setprio(0);                       \
  }

#define COMPUTE_TILE(cA_, cB_)                           \
  {                                                      \
    const char* ab_ = (const char*)As + (cA_);           \
    const char* bb_ = (const char*)Bs + (cB_);           \
    COMPUTE_HALF(ab_, bb_, 0)                            \
    COMPUTE_HALF(ab_, bb_, 1)                            \
  }

// fold expert e into output acc with gate weights from LDS (no VMEM — keeps vmcnt clean)
#define FOLD(e_)                                                      \
  {                                                                   \
    _Pragma("unroll")                                                 \
    for (int mi = 0; mi < 4; ++mi) {                                  \
      const int r_ = wrb + mi * 16 + lhi * 4;                         \
      const float w0 = wgs[(r_ + 0) * 8 + (e_)];                      \
      const float w1 = wgs[(r_ + 1) * 8 + (e_)];                      \
      const float w2 = wgs[(r_ + 2) * 8 + (e_)];                      \
      const float w3 = wgs[(r_ + 3) * 8 + (e_)];                      \
      _Pragma("unroll")                                               \
      for (int ni = 0; ni < 4; ++ni) {                                \
        accO[mi][ni][0] += w0 * acc[mi][ni][0];                       \
        accO[mi][ni][1] += w1 * acc[mi][ni][1];                       \
        accO[mi][ni][2] += w2 * acc[mi][ni][2];                       \
        accO[mi][ni][3] += w3 * acc[mi][ni][3];                       \
        acc[mi][ni] = fz;                                             \
      }                                                               \
    }                                                                 \
  }

#define ADVANCE                                          \
    curA += 32768; if (curA == 98304) curA = 0;          \
    curB += 16384; if (curB == 49152) curB = 0;          \
    stA  += 32768; if (stA  == 98304) stA  = 0;          \
    stB  += 16384; if (stB  == 49152) stB  = 0;

__global__ __launch_bounds__(512, 2) void moe_gemm_kernel(
    const u16* __restrict__ A,      // [T][H] bf16
    const u16* __restrict__ Wt,     // [E][H(d)][H(k)] bf16
    const float* __restrict__ wg,   // [T][E]
    const float* __restrict__ eb,   // [E][H]
    float* __restrict__ out)        // [T][H] fp32
{
  __shared__ u16 As[3 * BM * BK];   // 96 KB (ring of 3)
  __shared__ u16 Bs[3 * BN * BK];   // 48 KB
  __shared__ float wgs[BM * NE];    //  8 KB gate weights for this block's rows

  const int bid   = blockIdx.x;
  const int xcd   = bid & 7;
  const int local = bid >> 3;
  const int bm    = xcd * 4 + (local & 3);   // 32 bm, 4 per XCD
  const int bn    = local >> 2;              // 8 bn
  const int row0  = bm * BM;
  const int col0  = bn * BN;

  const int tid  = threadIdx.x;
  const int lane = tid & 63;
  const int wid  = tid >> 6;
  const int wr   = wid >> 1;        // 0..3
  const int wc   = wid & 1;         // 0..1
  const int l15  = lane & 15;
  const int lhi  = lane >> 4;
  const int wrb  = wr * 64;
  const int wcb  = wc * 64;

  // staging source: thread t covers row (t>>3) of each 64-row round, granule pre-swizzled
  const int row_in = tid >> 3;
  const int gsw    = (tid & 7) ^ ((tid >> 3) & 7);
  const u16* aSrc0 = A  + (size_t)(row0 + row_in) * HD + gsw * 8;
  const u16* bSrc0 = Wt + (size_t)(col0 + row_in) * HD + gsw * 8;

  // gate weights -> LDS (one f4 per thread covers 256 rows x 8 experts)
  {
    const f4 v = *(const f4*)(wg + (size_t)row0 * NE + tid * 4);
    *(f4*)&wgs[tid * 4] = v;
  }
  asm volatile("s_waitcnt vmcnt(0)" ::: "memory");   // wg loads retired: vmcnt clean

  const f4 fz = {0.f, 0.f, 0.f, 0.f};
  f4 acc[4][4], accO[4][4];
#pragma unroll
  for (int i = 0; i < 4; ++i)
#pragma unroll
    for (int j = 0; j < 4; ++j) { acc[i][j] = fz; accO[i][j] = fz; }

  // prologue: stage tiles 0 and 1 into ring slots 0 and 1 (12 loads in flight)
  STAGE(0, 0, 0)
  STAGE(1, 32768, 16384)

  int curA = 0, curB = 0;          // compute buffer byte offsets
  int stA = 65536, stB = 32768;    // stage target = (q+2)%3

  for (int q = 0; q < 126; ++q) {
    asm volatile("s_waitcnt vmcnt(6)" ::: "memory");   // tile q's 6 loads done; 6 stay in flight
    __builtin_amdgcn_s_barrier();                      // all waves' portions staged
    STAGE(q + 2, stA, stB)                             // issue-early into freed slot
    COMPUTE_TILE(curA, curB)
    asm volatile("s_waitcnt lgkmcnt(0)" ::: "memory"); // WAR safety before next barrier
    ADVANCE
    if ((q & 15) == 15) FOLD(q >> 4)
  }
  // q = 126: no staging left
  asm volatile("s_waitcnt vmcnt(6)" ::: "memory");
  __builtin_amdgcn_s_barrier();
  COMPUTE_TILE(curA, curB)
  asm volatile("s_waitcnt lgkmcnt(0)" ::: "memory");
  ADVANCE
  // q = 127: final tile, full drain
  asm volatile("s_waitcnt vmcnt(0)" ::: "memory");
  __builtin_amdgcn_s_barrier();
  COMPUTE_TILE(curA, curB)
  FOLD(7)

  // epilogue: gated bias + store (C/D: col = lane&15, row = (lane>>4)*4 + reg)
  float ebv[4][8];
#pragma unroll
  for (int ni = 0; ni < 4; ++ni) {
    const int d = col0 + wcb + ni * 16 + l15;
#pragma unroll
    for (int e2 = 0; e2 < NE; ++e2) ebv[ni][e2] = eb[(size_t)e2 * HD + d];
  }
#pragma unroll
  for (int mi = 0; mi < 4; ++mi) {
    const int r_ = wrb + mi * 16 + lhi * 4;
#pragma unroll
    for (int j = 0; j < 4; ++j) {
      const int t = row0 + r_ + j;
      const f4 wlo = *(const f4*)&wgs[(r_ + j) * 8];
      const f4 whi = *(const f4*)&wgs[(r_ + j) * 8 + 4];
#pragma unroll
      for (int ni = 0; ni < 4; ++ni) {
        const float bias =
            wlo[0] * ebv[ni][0] + wlo[1] * ebv[ni][1] +
            wlo[2] * ebv[ni][2] + wlo[3] * ebv[ni][3] +
            whi[0] * ebv[ni][4] + whi[1] * ebv[ni][5] +
            whi[2] * ebv[ni][6] + whi[3] * ebv[ni][7];
        const int d = col0 + wcb + ni * 16 + l15;
        out[(size_t)t * HD + d] = accO[mi][ni][j] + bias;
      }
    }
  }
}

extern "C" void kernel_launch(void* const* d_in, const int* in_sizes, int n_in,
                              void* d_out, int out_size, void* d_ws, size_t ws_size,
                              hipStream_t stream) {
  const float* x  = (const float*)d_in[0];   // [4,2048,1024]
  const float* gw = (const float*)d_in[1];   // [1024,8]
  const float* gb = (const float*)d_in[2];   // [8]
  const float* ew = (const float*)d_in[3];   // [8,1024,1024]
  const float* eb = (const float*)d_in[4];   // [8,1024]
  float* out = (float*)d_out;                // [4,2048,1024] fp32

  char* ws = (char*)d_ws;
  u16*   abf   = (u16*)ws;                                // 16 MB bf16 x
  u16*   wt    = (u16*)(ws + (size_t)16 * 1024 * 1024);   // 16 MB bf16 Wt
  float* wgate = (float*)(ws + (size_t)32 * 1024 * 1024); // 256 KB gate weights

  gate_conv_kernel<<<dim3(TTOK / 4), dim3(256), 0, stream>>>(x, gw, gb, wgate, abf);
  wconv_kernel<<<dim3(16, 16, 8), dim3(256), 0, stream>>>(ew, wt);
  moe_gemm_kernel<<<dim3((TTOK / BM) * (HD / BN)), dim3(512), 0, stream>>>(abf, wt, wgate, eb, out);
}

// Round 5
// 156.442 us; speedup vs baseline: 1.2421x; 1.2225x over previous
//
#include <hip/hip_runtime.h>
#include <stdint.h>

typedef unsigned short u16;
typedef short bf8 __attribute__((ext_vector_type(8)));   // 8 bf16 (bit pattern)
typedef float f4 __attribute__((ext_vector_type(4)));

#define TTOK 8192
#define HD   1024
#define NE   8

static __device__ __forceinline__ u16 f2bf(float f) {
  union { float f; uint32_t u; } v; v.f = f;
  return (u16)((v.u + 0x7fffu + ((v.u >> 16) & 1u)) >> 16);   // RNE
}

// ---------------- gating (fp32) + x -> bf16 conversion ----------------
__global__ __launch_bounds__(256) void gate_conv_kernel(
    const float* __restrict__ x, const float* __restrict__ gw,
    const float* __restrict__ gb, float* __restrict__ wout,
    u16* __restrict__ abf)
{
  const int t    = blockIdx.x * 4 + (threadIdx.x >> 6);
  const int lane = threadIdx.x & 63;
  const float* xr = x + (size_t)t * HD;
  float p[NE];
#pragma unroll
  for (int e = 0; e < NE; ++e) p[e] = 0.f;
#pragma unroll 4
  for (int h = lane; h < HD; h += 64) {
    const float xv = xr[h];
    abf[(size_t)t * HD + h] = f2bf(xv);
    const float* g = gw + (size_t)h * NE;
#pragma unroll
    for (int e = 0; e < NE; ++e) p[e] += xv * g[e];
  }
#pragma unroll
  for (int e = 0; e < NE; ++e) {
#pragma unroll
    for (int off = 32; off > 0; off >>= 1)
      p[e] += __shfl_xor(p[e], off, 64);
    p[e] += gb[e];
  }
  float m = p[0];
#pragma unroll
  for (int e = 1; e < NE; ++e) m = fmaxf(m, p[e]);
  float s = 0.f;
#pragma unroll
  for (int e = 0; e < NE; ++e) { p[e] = expf(p[e] - m); s += p[e]; }
  const float inv = 1.f / s;
  if (lane == 0) {
#pragma unroll
    for (int e = 0; e < NE; ++e) wout[t * NE + e] = p[e] * inv;
  }
}

// ------------- expert_w [E][H][H] fp32 -> Wt [E][d][h] bf16 (transposed) -------------
__global__ __launch_bounds__(256) void wconv_kernel(
    const float* __restrict__ ew, u16* __restrict__ wt)
{
  __shared__ u16 tile[64][66];
  const int e  = blockIdx.z;
  const int h0 = blockIdx.y * 64;
  const int d0 = blockIdx.x * 64;
  const int c  = threadIdx.x & 63;
  const int r0 = threadIdx.x >> 6;
  const float* src = ew + (size_t)e * HD * HD;
  u16* dst = wt + (size_t)e * HD * HD;
#pragma unroll
  for (int i = 0; i < 16; ++i) {
    const int r = i * 4 + r0;
    tile[r][c] = f2bf(src[(size_t)(h0 + r) * HD + d0 + c]);
  }
  __syncthreads();
#pragma unroll
  for (int i = 0; i < 16; ++i) {
    const int r = i * 4 + r0;
    dst[(size_t)(d0 + r) * HD + h0 + c] = tile[c][r];
  }
}

// ------- fused dense-MoE GEMM — m201-style per-phase interleave, ring-3, counted vmcnt -------
// out[t,d] = sum_e w[t,e] * ( sum_k A[t,k] * Wt[e][d][k] + eb[e][d] )
#define BM 128
#define BN 256
#define BK 64

#define MM(a_, b_, c_) __builtin_amdgcn_mfma_f32_16x16x32_bf16((a_), (b_), (c_), 0, 0, 0)

// frag read: row = waveBase + m*16 + l15 -> row&7 == l15&7; granule slot = (kk*4+lhi)^(l15&7)
#define LDFA(off_, m_, kk_) (*(const bf8*)((const char*)As + (off_) + \
    (size_t)(wrb + (m_) * 16 + l15) * 128 + ((((kk_) * 4 + lhi) ^ (l15 & 7)) << 4)))
#define LDFB(off_, n_, kk_) (*(const bf8*)((const char*)Bs + (off_) + \
    (size_t)(wcb + (n_) * 16 + l15) * 128 + ((((kk_) * 4 + lhi) ^ (l15 & 7)) << 4)))

#define GL(srcp_, dstp_) __builtin_amdgcn_global_load_lds( \
    (const __attribute__((address_space(1))) void*)(srcp_), \
    (__attribute__((address_space(3))) void*)(dstp_), 16, 0, 0)

// staging: 512 thr x 16B = 8KB/round; A = 2 rounds (128 rows), B = 4 rounds (256 rows)
// phase A stages rounds {A0, A1, B0}; phase B stages rounds {B1, B2, B3}
#define STAGE_PA(sq_)                                               \
  {                                                                 \
    const int se_ = (sq_) >> 4;                                     \
    const int sk_ = ((sq_) & 15) << 6;                              \
    const u16* as_ = aSrc0 + sk_;                                   \
    const u16* bs_ = bSrc0 + (size_t)se_ * (HD * HD) + sk_;         \
    char* ad_ = (char*)As + stA + tid * 16;                         \
    char* bd_ = (char*)Bs + stB + tid * 16;                         \
    GL(as_,         ad_);                                           \
    GL(as_ + 65536, ad_ + 8192);                                    \
    GL(bs_,         bd_);                                           \
  }
#define STAGE_PB(sq_)                                               \
  {                                                                 \
    const int se_ = (sq_) >> 4;                                     \
    const int sk_ = ((sq_) & 15) << 6;                              \
    const u16* bs_ = bSrc0 + (size_t)se_ * (HD * HD) + sk_;         \
    char* bd_ = (char*)Bs + stB + tid * 16;                         \
    GL(bs_ +  65536, bd_ +  8192);                                  \
    GL(bs_ + 131072, bd_ + 16384);                                  \
    GL(bs_ + 196608, bd_ + 24576);                                  \
  }

#define MFMA16                                            \
    acc[0][0] = MM(a0, b0, acc[0][0]);                    \
    acc[1][0] = MM(a1, b0, acc[1][0]);                    \
    acc[2][0] = MM(a2, b0, acc[2][0]);                    \
    acc[3][0] = MM(a3, b0, acc[3][0]);                    \
    acc[0][1] = MM(a0, b1, acc[0][1]);                    \
    acc[1][1] = MM(a1, b1, acc[1][1]);                    \
    acc[2][1] = MM(a2, b1, acc[2][1]);                    \
    acc[3][1] = MM(a3, b1, acc[3][1]);                    \
    acc[0][2] = MM(a0, b2, acc[0][2]);                    \
    acc[1][2] = MM(a1, b2, acc[1][2]);                    \
    acc[2][2] = MM(a2, b2, acc[2][2]);                    \
    acc[3][2] = MM(a3, b2, acc[3][2]);                    \
    acc[0][3] = MM(a0, b3, acc[0][3]);                    \
    acc[1][3] = MM(a1, b3, acc[1][3]);                    \
    acc[2][3] = MM(a2, b3, acc[2][3]);                    \
    acc[3][3] = MM(a3, b3, acc[3][3]);

#define READS(kk_)                                        \
    bf8 a0 = LDFA(curA, 0, kk_);                          \
    bf8 a1 = LDFA(curA, 1, kk_);                          \
    bf8 a2 = LDFA(curA, 2, kk_);                          \
    bf8 a3 = LDFA(curA, 3, kk_);                          \
    bf8 b0 = LDFB(curB, 0, kk_);                          \
    bf8 b1 = LDFB(curB, 1, kk_);                          \
    bf8 b2 = LDFB(curB, 2, kk_);                          \
    bf8 b3 = LDFB(curB, 3, kk_);

#define FOLD(e_)                                                      \
  {                                                                   \
    _Pragma("unroll")                                                 \
    for (int mi = 0; mi < 4; ++mi) {                                  \
      const int r_ = wrb + mi * 16 + lhi * 4;                         \
      const float w0 = wgs[(r_ + 0) * 9 + (e_)];                      \
      const float w1 = wgs[(r_ + 1) * 9 + (e_)];                      \
      const float w2 = wgs[(r_ + 2) * 9 + (e_)];                      \
      const float w3 = wgs[(r_ + 3) * 9 + (e_)];                      \
      _Pragma("unroll")                                               \
      for (int ni = 0; ni < 4; ++ni) {                                \
        accO[mi][ni][0] += w0 * acc[mi][ni][0];                       \
        accO[mi][ni][1] += w1 * acc[mi][ni][1];                       \
        accO[mi][ni][2] += w2 * acc[mi][ni][2];                       \
        accO[mi][ni][3] += w3 * acc[mi][ni][3];                       \
        acc[mi][ni] = fz;                                             \
      }                                                               \
    }                                                                 \
  }

#define ADVANCE                                          \
    curA += 16384; if (curA == 49152) curA = 0;          \
    curB += 32768; if (curB == 98304) curB = 0;          \
    stA  += 16384; if (stA  == 49152) stA  = 0;          \
    stB  += 32768; if (stB  == 98304) stB  = 0;

#define BAR       __builtin_amdgcn_s_barrier();
#define LGKM0     asm volatile("s_waitcnt lgkmcnt(0)" ::: "memory");
#define PRIO1     __builtin_amdgcn_s_setprio(1);
#define PRIO0     __builtin_amdgcn_s_setprio(0);

__global__ __launch_bounds__(512, 2) void moe_gemm_kernel(
    const u16* __restrict__ A,      // [T][H] bf16
    const u16* __restrict__ Wt,     // [E][H(d)][H(k)] bf16
    const float* __restrict__ wg,   // [T][E]
    const float* __restrict__ eb,   // [E][H]
    float* __restrict__ out)        // [T][H] fp32
{
  __shared__ u16 As[3 * BM * BK];   // 48 KB (ring of 3)
  __shared__ u16 Bs[3 * BN * BK];   // 96 KB
  __shared__ float wgs[BM * 9];     // 4.5 KB gate weights, stride-9 (bank-conflict-free)

  const int bid   = blockIdx.x;
  const int xcd   = bid & 7;
  const int local = bid >> 3;                // 0..31
  const int bm    = xcd * 8 + (local >> 2);  // 64 bm, 8 consecutive per XCD
  const int bn    = local & 3;               // 4 bn
  const int row0  = bm * BM;
  const int col0  = bn * BN;

  const int tid  = threadIdx.x;
  const int lane = tid & 63;
  const int wid  = tid >> 6;
  const int wr   = wid >> 2;        // 0..1
  const int wc   = wid & 3;         // 0..3
  const int l15  = lane & 15;
  const int lhi  = lane >> 4;
  const int wrb  = wr * 64;
  const int wcb  = wc * 64;

  // staging source: thread covers row (tid>>3) of each 64-row round, granule pre-swizzled
  const int row_in = tid >> 3;
  const int gsw    = (tid & 7) ^ ((tid >> 3) & 7);
  const u16* aSrc0 = A  + (size_t)(row0 + row_in) * HD + gsw * 8;
  const u16* bSrc0 = Wt + (size_t)(col0 + row_in) * HD + gsw * 8;

  // gate weights -> padded LDS table (128 rows x 8, stride 9)
  {
    const int i0 = tid, i1 = tid + 512;
    const float v0 = wg[(size_t)row0 * NE + i0];
    const float v1 = wg[(size_t)row0 * NE + i1];
    wgs[(i0 >> 3) * 9 + (i0 & 7)] = v0;
    wgs[(i1 >> 3) * 9 + (i1 & 7)] = v1;
  }
  LGKM0   // ds_writes drained (compiler auto-waits vmcnt before the ds_write)

  const f4 fz = {0.f, 0.f, 0.f, 0.f};
  f4 acc[4][4], accO[4][4];
#pragma unroll
  for (int i = 0; i < 4; ++i)
#pragma unroll
    for (int j = 0; j < 4; ++j) { acc[i][j] = fz; accO[i][j] = fz; }

  int curA = 0, curB = 0;          // compute slot byte offsets
  int stA = 32768, stB = 65536;    // stage target slot = (q+2)%3

  // prologue: stage tiles 0 and 1 into slots 0,1 (12 loads in flight)
  {
    int svA = stA, svB = stB;
    stA = 0; stB = 0;       STAGE_PA(0) STAGE_PB(0)
    stA = 16384; stB = 32768; STAGE_PA(1) STAGE_PB(1)
    stA = svA; stB = svB;
  }
  asm volatile("s_waitcnt vmcnt(6)" ::: "memory");   // tile 0 staged; tile 1 in flight
  BAR

  for (int q = 0; q < 126; ++q) {
    // ---- phase A (kk = 0) ----
    {
      READS(0)
      STAGE_PA(q + 2)
      BAR LGKM0 PRIO1
      MFMA16
      PRIO0 BAR
    }
    // ---- phase B (kk = 1) ----
    {
      READS(1)
      STAGE_PB(q + 2)
      BAR LGKM0 PRIO1
      MFMA16
      PRIO0
      asm volatile("s_waitcnt vmcnt(6)" ::: "memory");  // next tile's 6 rounds done; 6 in flight
      BAR
    }
    ADVANCE
    if ((q & 15) == 15) FOLD(q >> 4)
  }
  // q = 126: no staging left in flight beyond tile 127
  {
    { READS(0) BAR LGKM0 PRIO1 MFMA16 PRIO0 BAR }
    { READS(1) BAR LGKM0 PRIO1 MFMA16 PRIO0
      asm volatile("s_waitcnt vmcnt(0)" ::: "memory");  // tile 127 fully staged
      BAR }
    ADVANCE
  }
  // q = 127: final tile (no stage, no barriers needed)
  {
    { READS(0) MFMA16 }
    { READS(1) MFMA16 }
  }
  FOLD(7)

  // epilogue: gated bias + store (C/D: col = lane&15, row = (lane>>4)*4 + reg)
  float ebv[4][8];
#pragma unroll
  for (int ni = 0; ni < 4; ++ni) {
    const int d = col0 + wcb + ni * 16 + l15;
#pragma unroll
    for (int e2 = 0; e2 < NE; ++e2) ebv[ni][e2] = eb[(size_t)e2 * HD + d];
  }
#pragma unroll
  for (int mi = 0; mi < 4; ++mi) {
    const int r_ = wrb + mi * 16 + lhi * 4;
#pragma unroll
    for (int j = 0; j < 4; ++j) {
      const int t = row0 + r_ + j;
      const float* wrow = &wgs[(r_ + j) * 9];
#pragma unroll
      for (int ni = 0; ni < 4; ++ni) {
        const float bias =
            wrow[0] * ebv[ni][0] + wrow[1] * ebv[ni][1] +
            wrow[2] * ebv[ni][2] + wrow[3] * ebv[ni][3] +
            wrow[4] * ebv[ni][4] + wrow[5] * ebv[ni][5] +
            wrow[6] * ebv[ni][6] + wrow[7] * ebv[ni][7];
        const int d = col0 + wcb + ni * 16 + l15;
        out[(size_t)t * HD + d] = accO[mi][ni][j] + bias;
      }
    }
  }
}

extern "C" void kernel_launch(void* const* d_in, const int* in_sizes, int n_in,
                              void* d_out, int out_size, void* d_ws, size_t ws_size,
                              hipStream_t stream) {
  const float* x  = (const float*)d_in[0];   // [4,2048,1024]
  const float* gw = (const float*)d_in[1];   // [1024,8]
  const float* gb = (const float*)d_in[2];   // [8]
  const float* ew = (const float*)d_in[3];   // [8,1024,1024]
  const float* eb = (const float*)d_in[4];   // [8,1024]
  float* out = (float*)d_out;                // [4,2048,1024] fp32

  char* ws = (char*)d_ws;
  u16*   abf   = (u16*)ws;                                // 16 MB bf16 x
  u16*   wt    = (u16*)(ws + (size_t)16 * 1024 * 1024);   // 16 MB bf16 Wt
  float* wgate = (float*)(ws + (size_t)32 * 1024 * 1024); // 256 KB gate weights

  gate_conv_kernel<<<dim3(TTOK / 4), dim3(256), 0, stream>>>(x, gw, gb, wgate, abf);
  wconv_kernel<<<dim3(16, 16, 8), dim3(256), 0, stream>>>(ew, wt);
  moe_gemm_kernel<<<dim3((TTOK / BM) * (HD / BN)), dim3(512), 0, stream>>>(abf, wt, wgate, eb, out);
}